// Round 11
// baseline (36.391 us; speedup 1.0000x reference)
//
#include <hip/hip_runtime.h>
#include <math.h>

#define NPTS 262144
#define B_KB 4.71238898038469f      /* 1.5*pi */
#define B_KB2 22.2066099025f        /* B_KB^2 */
#define PI_F 3.14159265358979f
#define INV_2PI 0.15915494309f      /* 1/(2*pi) */
#define TWO_PI_OVER_N 0.01227184630309f /* 2*pi/512 */
#define NCOL 520                    /* padded complex row stride */
#define NCOLH 528                   /* padded f16 row stride */
#define PLANE (512 * NCOLH)         /* one parity plane, elements */
#define S_SCALE 1.37438953472e11f   /* 2^37: grid rescale into f16 range */
#define INV_S   7.27595761418e-12f  /* 2^-37 */

typedef _Float16 half8v __attribute__((ext_vector_type(8)));

__device__ __forceinline__ float i0f_dev(float x) {
    float ax = fabsf(x);
    if (ax < 3.75f) {
        float t = ax / 3.75f; t *= t;
        return 1.0f + t*(3.5156229f + t*(3.0899424f + t*(1.2067492f +
               t*(0.2659732f + t*(0.0360768f + t*0.0045813f)))));
    } else {
        float t = 3.75f / ax;
        float p = 0.39894228f + t*(0.01328592f + t*(0.00225319f + t*(-0.00157565f +
                  t*(0.00916281f + t*(-0.02057706f + t*(0.02635537f +
                  t*(-0.01647633f + t*0.00392377f)))))));
        return expf(ax) * p / sqrtf(ax);
    }
}

// Kaiser-Bessel window via raw v_exp/v_rcp: sinh(B*a)/(pi*a), a=sqrt(16-t^2)
__device__ __forceinline__ float phi_win(float t) {
    float s = 16.0f - t * t;
    if (s <= 0.0f) return 0.0f;
    float a = sqrtf(s);
    float ez = __expf(B_KB * a);
    return (ez - __builtin_amdgcn_rcpf(ez)) * INV_2PI * __builtin_amdgcn_rcpf(a);
}

// ---- Fused deconvolution + row FFT (rows with nonzero spectrum only). ----
// S_SCALE folded so the f16 grid lands in normal range; (-1)^(i1+i2) folded
// so the FFT output needs no ifftshift.
__global__ void rowfft_build(const float* __restrict__ fr,
                             const float* __restrict__ fi,
                             float2* __restrict__ g) {
    __shared__ float2 buf[512];
    int r = blockIdx.x;
    int i1 = (r < 128) ? r : r + 256;
    int k1 = (r < 128) ? r : r - 256;
    int tid = threadIdx.x;                 // 256 threads
    float a1 = TWO_PI_OVER_N * (float)k1;
    float ph1 = i0f_dev(4.0f * sqrtf(B_KB2 - a1 * a1));

    int k2 = tid - 128;                    // [-128, 128)
    int i2 = k2 & 511;
    float a2 = TWO_PI_OVER_N * (float)k2;
    float ph2 = i0f_dev(4.0f * sqrtf(B_KB2 - a2 * a2));
    float inv = S_SCALE / (ph1 * ph2);
    if ((i1 + i2) & 1) inv = -inv;
    int fidx = (k1 + 128) * 256 + (k2 + 128);
    float2 v = make_float2(fr[fidx] * inv, fi[fidx] * inv);

    buf[tid] = make_float2(0.0f, 0.0f);
    buf[tid + 256] = make_float2(0.0f, 0.0f);
    __syncthreads();
    int ri = (int)(__brev((unsigned)i2) >> 23);   // 9-bit reversal
    buf[ri] = v;
    __syncthreads();

    #pragma unroll
    for (int s = 1; s <= 9; ++s) {
        int half = 1 << (s - 1);
        int pos = tid & (half - 1);
        int j1 = ((tid >> (s - 1)) << s) | pos;
        float ang = -PI_F * (float)pos / (float)half;
        float sw, cw;
        __sincosf(ang, &sw, &cw);
        float2 u = buf[j1];
        float2 w = buf[j1 + half];
        float wr = cw * w.x - sw * w.y;
        float wi = cw * w.y + sw * w.x;
        buf[j1]        = make_float2(u.x + wr, u.y + wi);
        buf[j1 + half] = make_float2(u.x - wr, u.y - wi);
        __syncthreads();
    }
    long base = (long)i1 * NCOL;
    for (int j = tid; j < 512; j += 256) g[base + j] = buf[j];
    if (tid < 8) g[base + 512 + tid] = buf[tid];   // duplicate cols for padding
}

// ---- Column FFT (256 nonzero rows only); REAL part as f16, written
// TRANSPOSED (ghT[c][j]) so all global stores are lane-contiguous. ----
__global__ void colfft_f16T(const float2* __restrict__ g,
                            _Float16* __restrict__ ghT) {
    __shared__ float2 buf[512];
    int c = blockIdx.x;                    // 0..519
    int tid = threadIdx.x;                 // 256 threads
    buf[tid] = make_float2(0.0f, 0.0f);
    buf[tid + 256] = make_float2(0.0f, 0.0f);
    __syncthreads();
    int r = (tid < 128) ? tid : tid + 256;           // nonzero rows
    int rr = (int)(__brev((unsigned)r) >> 23);       // 9-bit reversal
    buf[rr] = g[(long)r * NCOL + c];
    __syncthreads();
    #pragma unroll
    for (int s = 1; s <= 9; ++s) {
        int half = 1 << (s - 1);
        int pos = tid & (half - 1);
        int j1 = ((tid >> (s - 1)) << s) | pos;
        float ang = -PI_F * (float)pos / (float)half;
        float sw, cw;
        __sincosf(ang, &sw, &cw);
        float2 u = buf[j1];
        float2 w = buf[j1 + half];
        float wr = cw * w.x - sw * w.y;
        float wi = cw * w.y + sw * w.x;
        buf[j1]        = make_float2(u.x + wr, u.y + wi);
        buf[j1 + half] = make_float2(u.x - wr, u.y - wi);
        __syncthreads();
    }
    long base = (long)c * 512;
    ghT[base + tid]       = (_Float16)buf[tid].x;        // coalesced
    ghT[base + tid + 256] = (_Float16)buf[tid + 256].x;  // coalesced
}

// ---- LDS-tiled transpose ghT[c][j] -> 4 parity planes gh[d][j][c-d].
// Coalesced reads AND coalesced writes. ----
__global__ void transpose_planes(const _Float16* __restrict__ ghT,
                                 _Float16* __restrict__ gh) {
    __shared__ _Float16 t[64][68];
    int c0 = blockIdx.x * 64;              // 0..8 (last tile partial)
    int j0 = blockIdx.y * 64;              // 0..7
    int lx = threadIdx.x & 63;
    int ly = threadIdx.x >> 6;             // 0..3
    for (int r = 0; r < 64; r += 4) {
        int c = c0 + ly + r;
        if (c < 520) t[ly + r][lx] = ghT[(long)c * 512 + j0 + lx];
    }
    __syncthreads();
    int c = c0 + lx;
    bool cok = (c < 520);
    for (int r = 0; r < 64; r += 4) {
        int j = j0 + ly + r;
        _Float16 v = t[lx][ly + r];
        long rb = (long)j * NCOLH;
        #pragma unroll
        for (int d = 0; d < 4; ++d) {
            if (cok && c >= d) gh[d * PLANE + rb + (c - d)] = v;  // coalesced
        }
    }
}

// ---- Split f16 gather: 2 threads per point, 4 window rows each, one
// dwordx4 (8 halves) per row -> 4 vmem insts/thread, 32 waves/CU. ----
__global__ __launch_bounds__(256)
void gather_f16split(const float2* __restrict__ x,
                     const _Float16* __restrict__ gh,
                     float* __restrict__ out) {
    int t = blockIdx.x * 256 + threadIdx.x;   // 0 .. 2*NPTS-1
    int m = t >> 1;
    int h = t & 1;
    float2 xv = x[m];
    float v1 = xv.x * 512.0f;
    float v2 = xv.y * 512.0f;
    float c1 = ceilf(v1), c2 = ceilf(v2);
    int b1 = (int)c1 - 4, b2 = (int)c2 - 4;
    float f1 = c1 - v1, f2 = c2 - v2;

    float phi2[8];
    #pragma unroll
    for (int j = 0; j < 8; ++j) phi2[j] = phi_win(4.0f - (float)j - f2);
    int cb = (b2 + 768) & 511;
    int d  = cb & 3;
    const _Float16* base = gh + d * PLANE + (cb - d);
    int w0 = h * 4;

    half8v rv[4];
    #pragma unroll
    for (int w = 0; w < 4; ++w) {
        int rowb = ((b1 + w0 + w + 768) & 511) * NCOLH;
        rv[w] = *reinterpret_cast<const half8v*>(base + rowb);
    }
    float acc = 0.0f;
    #pragma unroll
    for (int w = 0; w < 4; ++w) {
        float p1 = phi_win(4.0f - (float)(w0 + w) - f1);
        float rs = phi2[0]*(float)rv[w][0] + phi2[1]*(float)rv[w][1] +
                   phi2[2]*(float)rv[w][2] + phi2[3]*(float)rv[w][3] +
                   phi2[4]*(float)rv[w][4] + phi2[5]*(float)rv[w][5] +
                   phi2[6]*(float)rv[w][6] + phi2[7]*(float)rv[w][7];
        acc += p1 * rs;
    }
    acc += __shfl_xor(acc, 1);
    if (h == 0) out[m] = acc * INV_S;
}

// ================== fallback path (complex-capable, f32) ==================
__global__ void build_ghat(const float* __restrict__ fr,
                           const float* __restrict__ fi,
                           float2* __restrict__ g, int ldg) {
    int idx = blockIdx.x * 256 + threadIdx.x;
    int i1 = idx >> 9;
    int i2 = idx & 511;
    float2 val = make_float2(0.0f, 0.0f);
    int k1 = 0, k2 = 0;
    bool ok = true;
    if (i1 < 128) k1 = i1; else if (i1 >= 384) k1 = i1 - 512; else ok = false;
    if (ok) { if (i2 < 128) k2 = i2; else if (i2 >= 384) k2 = i2 - 512; else ok = false; }
    if (ok) {
        float a1 = TWO_PI_OVER_N * (float)k1;
        float a2 = TWO_PI_OVER_N * (float)k2;
        float ph1 = i0f_dev(4.0f * sqrtf(B_KB2 - a1*a1));
        float ph2 = i0f_dev(4.0f * sqrtf(B_KB2 - a2*a2));
        float inv = 1.0f / (ph1 * ph2);
        if ((i1 + i2) & 1) inv = -inv;
        int fidx = (k1 + 128) * 256 + (k2 + 128);
        val.x = fr[fidx] * inv;
        val.y = fi[fidx] * inv;
    }
    g[i1 * ldg + i2] = val;
}

__global__ void fft_lines(float2* __restrict__ g, int line_stride,
                          int elem_stride, int ndup) {
    __shared__ float2 buf[512];
    int line = blockIdx.x;
    int tid = threadIdx.x;
    long base = (long)line * line_stride;
    for (int j = tid; j < 512; j += 256) {
        int rj = (int)(__brev((unsigned)j) >> 23);
        buf[rj] = g[base + (long)j * elem_stride];
    }
    __syncthreads();
    #pragma unroll
    for (int s = 1; s <= 9; ++s) {
        int half = 1 << (s - 1);
        int pos = tid & (half - 1);
        int i1 = ((tid >> (s - 1)) << s) | pos;
        float ang = -PI_F * (float)pos / (float)half;
        float sw, cw;
        __sincosf(ang, &sw, &cw);
        float2 u = buf[i1];
        float2 v = buf[i1 + half];
        float wr = cw * v.x - sw * v.y;
        float wi = cw * v.y + sw * v.x;
        buf[i1]        = make_float2(u.x + wr, u.y + wi);
        buf[i1 + half] = make_float2(u.x - wr, u.y - wi);
        __syncthreads();
    }
    for (int j = tid; j < 512; j += 256) g[base + (long)j * elem_stride] = buf[j];
    for (int j = tid; j < ndup; j += 256) g[base + 512 + j] = buf[j];
}

template<int COMPLEX>
__global__ __launch_bounds__(256, 4)
void gather_pad(const float2* __restrict__ x,
                const float2* __restrict__ g,
                float* __restrict__ out) {
    int m = blockIdx.x * 256 + threadIdx.x;
    float2 xv = x[m];
    float v1 = xv.x * 512.0f;
    float v2 = xv.y * 512.0f;
    float c1 = ceilf(v1), c2 = ceilf(v2);
    int b1 = (int)c1 - 4, b2 = (int)c2 - 4;
    float f1 = c1 - v1, f2 = c2 - v2;

    float phi1[8], phi2[8];
    int rowb[8];
    #pragma unroll
    for (int w = 0; w < 8; ++w) {
        phi1[w] = phi_win(4.0f - (float)w - f1);
        phi2[w] = phi_win(4.0f - (float)w - f2);
        rowb[w] = ((b1 + w + 768) & 511) * NCOL;
    }
    int cb = (b2 + 768) & 511;

    float accx = 0.0f, accy = 0.0f;
    #pragma unroll
    for (int w1 = 0; w1 < 8; ++w1) {
        const float4* p = reinterpret_cast<const float4*>(g + rowb[w1] + cb);
        float4 va = p[0], vb = p[1], vc = p[2], vd = p[3];
        float p1 = phi1[w1];
        accx += p1 * (phi2[0]*va.x + phi2[1]*va.z + phi2[2]*vb.x + phi2[3]*vb.z +
                      phi2[4]*vc.x + phi2[5]*vc.z + phi2[6]*vd.x + phi2[7]*vd.z);
        if (COMPLEX)
            accy += p1 * (phi2[0]*va.y + phi2[1]*va.w + phi2[2]*vb.y + phi2[3]*vb.w +
                          phi2[4]*vc.y + phi2[5]*vc.w + phi2[6]*vd.y + phi2[7]*vd.w);
    }
    if (COMPLEX) ((float2*)out)[m] = make_float2(accx, accy);
    else out[m] = accx;
}

extern "C" void kernel_launch(void* const* d_in, const int* in_sizes, int n_in,
                              void* d_out, int out_size, void* d_ws, size_t ws_size,
                              hipStream_t stream) {
    const float* x  = (const float*)d_in[0];
    const float* fr = (const float*)d_in[1];
    const float* fi = (const float*)d_in[2];
    int cplx = (out_size >= 2 * NPTS) ? 1 : 0;

    size_t g_bytes   = (size_t)512 * NCOL * sizeof(float2);    // 2,129,920
    size_t ghT_bytes = (size_t)520 * 512 * sizeof(_Float16);   //   532,480
    size_t gh_bytes  = (size_t)4 * PLANE * sizeof(_Float16);   // 2,162,688
    char* ws = (char*)d_ws;
    float2*   g   = (float2*)ws;
    _Float16* ghT = (_Float16*)(ws + g_bytes);
    _Float16* gh  = (_Float16*)(ws + g_bytes + ghT_bytes);
    size_t need = g_bytes + ghT_bytes + gh_bytes;

    if (!cplx && ws_size >= need) {
        // Fast path: fused build+rowFFT, coalesced f16 colFFT + plane
        // transpose, 2-thread-per-point 4-load gather at 32 waves/CU.
        rowfft_build<<<256, 256, 0, stream>>>(fr, fi, g);
        colfft_f16T<<<NCOL, 256, 0, stream>>>(g, ghT);
        transpose_planes<<<dim3(9, 8), 256, 0, stream>>>(ghT, gh);
        gather_f16split<<<2048, 256, 0, stream>>>((const float2*)x, gh, (float*)d_out);
    } else if (ws_size >= g_bytes) {
        build_ghat<<<1024, 256, 0, stream>>>(fr, fi, g, NCOL);
        fft_lines<<<512, 256, 0, stream>>>(g, NCOL, 1, 8);
        fft_lines<<<NCOL, 256, 0, stream>>>(g, 1, NCOL, 0);
        if (cplx)
            gather_pad<1><<<1024, 256, 0, stream>>>((const float2*)x, g, (float*)d_out);
        else
            gather_pad<0><<<1024, 256, 0, stream>>>((const float2*)x, g, (float*)d_out);
    } else {
        build_ghat<<<1024, 256, 0, stream>>>(fr, fi, g, 512);
        fft_lines<<<512, 256, 0, stream>>>(g, 512, 1, 0);
        fft_lines<<<512, 256, 0, stream>>>(g, 1, 512, 0);
        if (cplx)
            gather_pad<1><<<1024, 256, 0, stream>>>((const float2*)x, g, (float*)d_out);
        else
            gather_pad<0><<<1024, 256, 0, stream>>>((const float2*)x, g, (float*)d_out);
    }
}

// Round 12
// 28.253 us; speedup vs baseline: 1.2880x; 1.2880x over previous
//
#include <hip/hip_runtime.h>
#include <math.h>

#define NPTS 262144
#define B_KB 4.71238898038469f      /* 1.5*pi */
#define B_KB2 22.2066099025f        /* B_KB^2 */
#define PI_F 3.14159265358979f
#define INV_2PI 0.15915494309f      /* 1/(2*pi) */
#define TWO_PI_OVER_N 0.01227184630309f /* 2*pi/512 */
#define NCOL 520                    /* padded row stride: 512 + 8 dup cols */
#define S_SCALE 1.37438953472e11f   /* 2^37: grid rescale into f16 range */
#define INV_S   7.27595761418e-12f  /* 2^-37 */

typedef _Float16 half8v __attribute__((ext_vector_type(8)));
typedef _Float16 half4v __attribute__((ext_vector_type(4)));

__device__ __forceinline__ float i0f_dev(float x) {
    float ax = fabsf(x);
    if (ax < 3.75f) {
        float t = ax / 3.75f; t *= t;
        return 1.0f + t*(3.5156229f + t*(3.0899424f + t*(1.2067492f +
               t*(0.2659732f + t*(0.0360768f + t*0.0045813f)))));
    } else {
        float t = 3.75f / ax;
        float p = 0.39894228f + t*(0.01328592f + t*(0.00225319f + t*(-0.00157565f +
                  t*(0.00916281f + t*(-0.02057706f + t*(0.02635537f +
                  t*(-0.01647633f + t*0.00392377f)))))));
        return expf(ax) * p / sqrtf(ax);
    }
}

// Kaiser-Bessel window via raw v_exp/v_rcp: sinh(B*a)/(pi*a), a=sqrt(16-t^2)
__device__ __forceinline__ float phi_win(float t) {
    float s = 16.0f - t * t;
    if (s <= 0.0f) return 0.0f;
    float a = sqrtf(s);
    float ez = __expf(B_KB * a);
    return (ez - __builtin_amdgcn_rcpf(ez)) * INV_2PI * __builtin_amdgcn_rcpf(a);
}

// ---- Fused deconvolution + row FFT (rows with nonzero spectrum only). ----
// S_SCALE folded so the f16 grid lands in normal range; (-1)^(i1+i2) folded
// so the FFT output needs no ifftshift.
__global__ void rowfft_build(const float* __restrict__ fr,
                             const float* __restrict__ fi,
                             float2* __restrict__ g) {
    __shared__ float2 buf[512];
    int r = blockIdx.x;
    int i1 = (r < 128) ? r : r + 256;
    int k1 = (r < 128) ? r : r - 256;
    int tid = threadIdx.x;                 // 256 threads
    float a1 = TWO_PI_OVER_N * (float)k1;
    float ph1 = i0f_dev(4.0f * sqrtf(B_KB2 - a1 * a1));

    int k2 = tid - 128;                    // [-128, 128)
    int i2 = k2 & 511;
    float a2 = TWO_PI_OVER_N * (float)k2;
    float ph2 = i0f_dev(4.0f * sqrtf(B_KB2 - a2 * a2));
    float inv = S_SCALE / (ph1 * ph2);
    if ((i1 + i2) & 1) inv = -inv;
    int fidx = (k1 + 128) * 256 + (k2 + 128);
    float2 v = make_float2(fr[fidx] * inv, fi[fidx] * inv);

    buf[tid] = make_float2(0.0f, 0.0f);
    buf[tid + 256] = make_float2(0.0f, 0.0f);
    __syncthreads();
    int ri = (int)(__brev((unsigned)i2) >> 23);   // 9-bit reversal
    buf[ri] = v;
    __syncthreads();

    #pragma unroll
    for (int s = 1; s <= 9; ++s) {
        int half = 1 << (s - 1);
        int pos = tid & (half - 1);
        int j1 = ((tid >> (s - 1)) << s) | pos;
        float ang = -PI_F * (float)pos / (float)half;
        float sw, cw;
        __sincosf(ang, &sw, &cw);
        float2 u = buf[j1];
        float2 w = buf[j1 + half];
        float wr = cw * w.x - sw * w.y;
        float wi = cw * w.y + sw * w.x;
        buf[j1]        = make_float2(u.x + wr, u.y + wi);
        buf[j1 + half] = make_float2(u.x - wr, u.y - wi);
        __syncthreads();
    }
    long base = (long)i1 * NCOL;
    for (int j = tid; j < 512; j += 256) g[base + j] = buf[j];
    if (tid < 8) g[base + 512 + tid] = buf[tid];   // duplicate cols for padding
}

// ---- Column FFT over the 256 nonzero rows only; REAL part to f32 grid. ----
__global__ void colfft_real(const float2* __restrict__ g,
                            float* __restrict__ gre) {
    __shared__ float2 buf[512];
    int c = blockIdx.x;                    // 0..519
    int tid = threadIdx.x;                 // 256 threads
    buf[tid] = make_float2(0.0f, 0.0f);
    buf[tid + 256] = make_float2(0.0f, 0.0f);
    __syncthreads();
    int r = (tid < 128) ? tid : tid + 256;           // nonzero rows
    int rr = (int)(__brev((unsigned)r) >> 23);       // 9-bit reversal
    buf[rr] = g[(long)r * NCOL + c];
    __syncthreads();
    #pragma unroll
    for (int s = 1; s <= 9; ++s) {
        int half = 1 << (s - 1);
        int pos = tid & (half - 1);
        int j1 = ((tid >> (s - 1)) << s) | pos;
        float ang = -PI_F * (float)pos / (float)half;
        float sw, cw;
        __sincosf(ang, &sw, &cw);
        float2 u = buf[j1];
        float2 w = buf[j1 + half];
        float wr = cw * w.x - sw * w.y;
        float wi = cw * w.y + sw * w.x;
        buf[j1]        = make_float2(u.x + wr, u.y + wi);
        buf[j1 + half] = make_float2(u.x - wr, u.y - wi);
        __syncthreads();
    }
    for (int j = tid; j < 512; j += 256) gre[(long)j * NCOL + c] = buf[j].x;
}

// ---- Build 4 quad-row-interleaved f16 copies:
// qg[s][rq][c][r] = (f16)gre[(4*rq+s+r) & 511][c], r=0..3 packed per column.
// A point's 8x8 window = 2 contiguous 64B segments (quads rq0, rq0+1). ----
__global__ void build_quads(const float* __restrict__ gre,
                            _Float16* __restrict__ qg) {
    int u = blockIdx.x;                    // 0..511: s = u>>7, rq = u&127
    int s = u >> 7, rq = u & 127;
    int tid = threadIdx.x;                 // 256
    int r0 = 4 * rq + s;
    const float* g0 = gre + (long)((r0    ) & 511) * NCOL;
    const float* g1 = gre + (long)((r0 + 1) & 511) * NCOL;
    const float* g2 = gre + (long)((r0 + 2) & 511) * NCOL;
    const float* g3 = gre + (long)((r0 + 3) & 511) * NCOL;
    _Float16* outb = qg + ((long)u * NCOL << 2);
    for (int c = tid; c < NCOL; c += 256) {
        half4v w;
        w[0] = (_Float16)g0[c];
        w[1] = (_Float16)g1[c];
        w[2] = (_Float16)g2[c];
        w[3] = (_Float16)g3[c];
        *reinterpret_cast<half4v*>(outb + ((long)c << 2)) = w;   // coalesced 8B
    }
}

// ---- Quad gather: 2 threads per point; thread h loads quad rq0+h as
// 4 x dwordx4 (64B contiguous). 3-4 cache-line touches per point total. ----
__global__ __launch_bounds__(256)
void gather_quads(const float2* __restrict__ x,
                  const _Float16* __restrict__ qg,
                  float* __restrict__ out) {
    int t = blockIdx.x * 256 + threadIdx.x;   // 0 .. 2*NPTS-1
    int m = t >> 1;
    int h = t & 1;
    float2 xv = x[m];
    float v1 = xv.x * 512.0f;
    float v2 = xv.y * 512.0f;
    float c1 = ceilf(v1), c2 = ceilf(v2);
    int b1 = (int)c1 - 4, b2 = (int)c2 - 4;
    float f1 = c1 - v1, f2 = c2 - v2;

    float phi2[8];
    #pragma unroll
    for (int j = 0; j < 8; ++j) phi2[j] = phi_win(4.0f - (float)j - f2);
    float phi1h[4];
    #pragma unroll
    for (int r = 0; r < 4; ++r)
        phi1h[r] = phi_win(4.0f - (float)(4 * h + r) - f1);

    int b1p = (b1 + 768) & 511;
    int b2p = (b2 + 768) & 511;
    int s  = b1p & 3;
    int rq = ((b1p >> 2) + h) & 127;
    const _Float16* base = qg + (((long)(s * 128 + rq) * NCOL + b2p) << 2);

    half8v rv[4];                           // 4 x 16B, contiguous 64B total
    #pragma unroll
    for (int li = 0; li < 4; ++li)
        rv[li] = *reinterpret_cast<const half8v*>(base + (li << 3));

    float acc = 0.0f;
    #pragma unroll
    for (int li = 0; li < 4; ++li) {
        #pragma unroll
        for (int k = 0; k < 8; ++k) {
            int j = (li << 1) + (k >> 2);   // window col
            int r = k & 3;                  // row within quad
            acc += (float)rv[li][k] * (phi1h[r] * phi2[j]);
        }
    }
    acc += __shfl_xor(acc, 1);
    if (h == 0) out[m] = acc * INV_S;
}

// ================== fallback path (complex-capable, f32) ==================
__global__ void build_ghat(const float* __restrict__ fr,
                           const float* __restrict__ fi,
                           float2* __restrict__ g, int ldg) {
    int idx = blockIdx.x * 256 + threadIdx.x;
    int i1 = idx >> 9;
    int i2 = idx & 511;
    float2 val = make_float2(0.0f, 0.0f);
    int k1 = 0, k2 = 0;
    bool ok = true;
    if (i1 < 128) k1 = i1; else if (i1 >= 384) k1 = i1 - 512; else ok = false;
    if (ok) { if (i2 < 128) k2 = i2; else if (i2 >= 384) k2 = i2 - 512; else ok = false; }
    if (ok) {
        float a1 = TWO_PI_OVER_N * (float)k1;
        float a2 = TWO_PI_OVER_N * (float)k2;
        float ph1 = i0f_dev(4.0f * sqrtf(B_KB2 - a1*a1));
        float ph2 = i0f_dev(4.0f * sqrtf(B_KB2 - a2*a2));
        float inv = 1.0f / (ph1 * ph2);
        if ((i1 + i2) & 1) inv = -inv;
        int fidx = (k1 + 128) * 256 + (k2 + 128);
        val.x = fr[fidx] * inv;
        val.y = fi[fidx] * inv;
    }
    g[i1 * ldg + i2] = val;
}

__global__ void fft_lines(float2* __restrict__ g, int line_stride,
                          int elem_stride, int ndup) {
    __shared__ float2 buf[512];
    int line = blockIdx.x;
    int tid = threadIdx.x;
    long base = (long)line * line_stride;
    for (int j = tid; j < 512; j += 256) {
        int rj = (int)(__brev((unsigned)j) >> 23);
        buf[rj] = g[base + (long)j * elem_stride];
    }
    __syncthreads();
    #pragma unroll
    for (int s = 1; s <= 9; ++s) {
        int half = 1 << (s - 1);
        int pos = tid & (half - 1);
        int i1 = ((tid >> (s - 1)) << s) | pos;
        float ang = -PI_F * (float)pos / (float)half;
        float sw, cw;
        __sincosf(ang, &sw, &cw);
        float2 u = buf[i1];
        float2 v = buf[i1 + half];
        float wr = cw * v.x - sw * v.y;
        float wi = cw * v.y + sw * v.x;
        buf[i1]        = make_float2(u.x + wr, u.y + wi);
        buf[i1 + half] = make_float2(u.x - wr, u.y - wi);
        __syncthreads();
    }
    for (int j = tid; j < 512; j += 256) g[base + (long)j * elem_stride] = buf[j];
    for (int j = tid; j < ndup; j += 256) g[base + 512 + j] = buf[j];
}

template<int COMPLEX>
__global__ __launch_bounds__(256, 4)
void gather_pad(const float2* __restrict__ x,
                const float2* __restrict__ g,
                float* __restrict__ out) {
    int m = blockIdx.x * 256 + threadIdx.x;
    float2 xv = x[m];
    float v1 = xv.x * 512.0f;
    float v2 = xv.y * 512.0f;
    float c1 = ceilf(v1), c2 = ceilf(v2);
    int b1 = (int)c1 - 4, b2 = (int)c2 - 4;
    float f1 = c1 - v1, f2 = c2 - v2;

    float phi1[8], phi2[8];
    int rowb[8];
    #pragma unroll
    for (int w = 0; w < 8; ++w) {
        phi1[w] = phi_win(4.0f - (float)w - f1);
        phi2[w] = phi_win(4.0f - (float)w - f2);
        rowb[w] = ((b1 + w + 768) & 511) * NCOL;
    }
    int cb = (b2 + 768) & 511;

    float accx = 0.0f, accy = 0.0f;
    #pragma unroll
    for (int w1 = 0; w1 < 8; ++w1) {
        const float4* p = reinterpret_cast<const float4*>(g + rowb[w1] + cb);
        float4 va = p[0], vb = p[1], vc = p[2], vd = p[3];
        float p1 = phi1[w1];
        accx += p1 * (phi2[0]*va.x + phi2[1]*va.z + phi2[2]*vb.x + phi2[3]*vb.z +
                      phi2[4]*vc.x + phi2[5]*vc.z + phi2[6]*vd.x + phi2[7]*vd.z);
        if (COMPLEX)
            accy += p1 * (phi2[0]*va.y + phi2[1]*va.w + phi2[2]*vb.y + phi2[3]*vb.w +
                          phi2[4]*vc.y + phi2[5]*vc.w + phi2[6]*vd.y + phi2[7]*vd.w);
    }
    if (COMPLEX) ((float2*)out)[m] = make_float2(accx, accy);
    else out[m] = accx;
}

extern "C" void kernel_launch(void* const* d_in, const int* in_sizes, int n_in,
                              void* d_out, int out_size, void* d_ws, size_t ws_size,
                              hipStream_t stream) {
    const float* x  = (const float*)d_in[0];
    const float* fr = (const float*)d_in[1];
    const float* fi = (const float*)d_in[2];
    int cplx = (out_size >= 2 * NPTS) ? 1 : 0;

    size_t g_bytes   = (size_t)512 * NCOL * sizeof(float2);   // 2,129,920
    size_t gre_bytes = (size_t)512 * NCOL * sizeof(float);    // 1,064,960
    size_t qg_bytes  = (size_t)512 * NCOL * 4 * sizeof(_Float16); // 2,129,920
    char* ws = (char*)d_ws;
    float2*   g   = (float2*)ws;
    float*    gre = (float*)(ws + g_bytes);
    _Float16* qg  = (_Float16*)(ws + g_bytes + gre_bytes);
    size_t need = g_bytes + gre_bytes + qg_bytes;

    if (!cplx && ws_size >= need) {
        // Fast path: fused build+rowFFT, f32 colFFT, quad-interleave copy,
        // contiguous-window gather at 32 waves/CU.
        rowfft_build<<<256, 256, 0, stream>>>(fr, fi, g);
        colfft_real<<<NCOL, 256, 0, stream>>>(g, gre);
        build_quads<<<512, 256, 0, stream>>>(gre, qg);
        gather_quads<<<2048, 256, 0, stream>>>((const float2*)x, qg, (float*)d_out);
    } else if (ws_size >= g_bytes) {
        build_ghat<<<1024, 256, 0, stream>>>(fr, fi, g, NCOL);
        fft_lines<<<512, 256, 0, stream>>>(g, NCOL, 1, 8);
        fft_lines<<<NCOL, 256, 0, stream>>>(g, 1, NCOL, 0);
        if (cplx)
            gather_pad<1><<<1024, 256, 0, stream>>>((const float2*)x, g, (float*)d_out);
        else
            gather_pad<0><<<1024, 256, 0, stream>>>((const float2*)x, g, (float*)d_out);
    } else {
        build_ghat<<<1024, 256, 0, stream>>>(fr, fi, g, 512);
        fft_lines<<<512, 256, 0, stream>>>(g, 512, 1, 0);
        fft_lines<<<512, 256, 0, stream>>>(g, 1, 512, 0);
        if (cplx)
            gather_pad<1><<<1024, 256, 0, stream>>>((const float2*)x, g, (float*)d_out);
        else
            gather_pad<0><<<1024, 256, 0, stream>>>((const float2*)x, g, (float*)d_out);
    }
}